// Round 6
// baseline (19997.012 us; speedup 1.0000x reference)
//
#include <hip/hip_runtime.h>
#include <math.h>

// Problem constants
#define BB 64
#define SS 512
#define DD 256
#define HH 512
#define GG 1536   // 3H
#define SC 128    // steps per x_proj chunk
#define NCHUNK 4

// d_out scratch layout (float offsets) — d_out is dead until attn_fused rewrites it
#define OUT_OFF_WIHT 0UL
#define OUT_SZ_WIHT  (256UL * 1536UL)          // 393216 floats
#define OUT_OFF_WRZ  (OUT_OFF_WIHT + OUT_SZ_WIHT)   // float2[512*512] = 524288 floats
#define OUT_SZ_WRZ   (512UL * 512UL * 2UL)
#define OUT_OFF_WN   (OUT_OFF_WRZ + OUT_SZ_WRZ)     // float[512*512] = 262144 floats
#define OUT_SZ_WN    (512UL * 512UL)
#define OUT_OFF_XC   (OUT_OFF_WN + OUT_SZ_WN)
#define OUT_SZ_XC    ((size_t)SC * BB * GG)    // 12582912 -> total 13762560 < 16777216

__device__ __forceinline__ float sigmoidf_(float x) {
  return 1.f / (1.f + expf(-x));
}

// ---------------- transpose: out[c][r] = in[r][c] ----------------
__global__ __launch_bounds__(256) void transpose_k(const float* __restrict__ in,
                                                   float* __restrict__ out,
                                                   int R, int C) {
  __shared__ float tile[32][33];
  int bx = blockIdx.x * 32;  // C base
  int by = blockIdx.y * 32;  // R base
  int tx = threadIdx.x, ty = threadIdx.y;  // 32 x 8
  for (int i = ty; i < 32; i += 8) {
    int r = by + i, c = bx + tx;
    if (r < R && c < C) tile[i][tx] = in[(size_t)r * C + c];
  }
  __syncthreads();
  for (int i = ty; i < 32; i += 8) {
    int c = bx + i, r = by + tx;
    if (c < C && r < R) out[(size_t)c * R + r] = tile[tx][i];
  }
}

// -------- pack W_hh [1536][512] into gate-interleaved k-major streams --------
// Wrz[k*512+j] = {W_hh[j][k], W_hh[512+j][k]};  Wn[k*512+j] = W_hh[1024+j][k]
__global__ __launch_bounds__(256) void pack_whh(const float* __restrict__ W_hh,
                                                float2* __restrict__ Wrz,
                                                float* __restrict__ Wn) {
  int idx = blockIdx.x * 256 + threadIdx.x;  // over 512*512
  int k = idx >> 9, j = idx & 511;
  float2 rz = {W_hh[(size_t)j * HH + k], W_hh[(size_t)(HH + j) * HH + k]};
  Wrz[idx] = rz;
  Wn[idx] = W_hh[(size_t)(2 * HH + j) * HH + k];
}

// -------- x_proj chunk GEMM: xc[sl][b][g] = inp[b][s0+sl][:] . WihT[:][g] + b_ih[g]
__global__ __launch_bounds__(256) void xproj_gemm(const float* __restrict__ inp,
                                                  const float* __restrict__ WihT,
                                                  const float* __restrict__ b_ih,
                                                  float* __restrict__ xc, int s0) {
  const int sl = blockIdx.y;
  const int n0 = blockIdx.x * 64;
  const int srow = s0 + sl;
  const int tx = threadIdx.x & 15, ty = threadIdx.x >> 4;
  __shared__ float As[64][36];
  __shared__ float Bs[32][68];
  float acc[4][4] = {};

  for (int k0 = 0; k0 < DD; k0 += 32) {
#pragma unroll
    for (int i = 0; i < 2; ++i) {  // stage A 64x32 (rows = batches)
      int f = threadIdx.x + 256 * i;
      int m = f >> 3, kq = (f & 7) << 2;
      *(float4*)&As[m][kq] =
          *(const float4*)&inp[((size_t)m * SS + srow) * DD + k0 + kq];
    }
#pragma unroll
    for (int i = 0; i < 2; ++i) {  // stage B 32x64
      int f = threadIdx.x + 256 * i;
      int n4 = (f & 15) << 2, kk = f >> 4;
      *(float4*)&Bs[kk][n4] =
          *(const float4*)&WihT[(size_t)(k0 + kk) * GG + n0 + n4];
    }
    __syncthreads();
#pragma unroll
    for (int kk = 0; kk < 32; ++kk) {
      float a[4];
#pragma unroll
      for (int i = 0; i < 4; ++i) a[i] = As[ty * 4 + i][kk];
      float4 b4 = *(const float4*)&Bs[kk][tx * 4];
      float bb[4] = {b4.x, b4.y, b4.z, b4.w};
#pragma unroll
      for (int i = 0; i < 4; ++i)
#pragma unroll
        for (int j = 0; j < 4; ++j) acc[i][j] = fmaf(a[i], bb[j], acc[i][j]);
    }
    __syncthreads();
  }
  const float g0 = b_ih[n0 + tx * 4 + 0], g1 = b_ih[n0 + tx * 4 + 1];
  const float g2 = b_ih[n0 + tx * 4 + 2], g3 = b_ih[n0 + tx * 4 + 3];
#pragma unroll
  for (int i = 0; i < 4; ++i) {
    int m = ty * 4 + i;  // batch
    float4 o = {acc[i][0] + g0, acc[i][1] + g1, acc[i][2] + g2, acc[i][3] + g3};
    *(float4*)&xc[((size_t)sl * BB + m) * GG + n0 + tx * 4] = o;
  }
}

// ---------------- GRU scan chunk: 1 WG/batch, 1024 threads, split-k ----------
// thread t: j = t&511 (hidden unit), half = t>>9 (k range half*256..+256)
__global__ __launch_bounds__(1024) void gru_scan_chunk(const float* __restrict__ xc,
                                                       const float2* __restrict__ Wrz,
                                                       const float* __restrict__ Wn,
                                                       const float* __restrict__ b_hh,
                                                       float* __restrict__ h_all,
                                                       int s0) {
  const int b = blockIdx.x;
  const int t = threadIdx.x;
  const int j = t & 511;
  const int half = t >> 9;
  const int k0 = half << 8;  // 0 or 256
  __shared__ float hs[HH];
  __shared__ float red[3 * HH];  // half-1 partials: [gate][j]
  float hprev = 0.f;
  if (t < HH) {
    hprev = (s0 == 0) ? 0.f : h_all[((size_t)b * SS + (s0 - 1)) * HH + t];
    hs[t] = hprev;
  }
  __syncthreads();
  const float bh_r = b_hh[j], bh_z = b_hh[HH + j], bh_n = b_hh[2 * HH + j];
  float* hout = h_all + (size_t)b * SS * HH;

  for (int sl = 0; sl < SC; ++sl) {
    float ar = 0.f, az = 0.f, an = 0.f;
    const float2* wrz = Wrz + (size_t)k0 * HH + j;
    const float* wn = Wn + (size_t)k0 * HH + j;
#pragma unroll 4
    for (int kk = 0; kk < 256; kk += 4) {
      float4 h4 = *(const float4*)&hs[k0 + kk];  // broadcast read
      float2 w0 = wrz[0 * HH], w1 = wrz[1 * HH], w2 = wrz[2 * HH], w3 = wrz[3 * HH];
      float n0 = wn[0 * HH], n1 = wn[1 * HH], n2 = wn[2 * HH], n3 = wn[3 * HH];
      ar = fmaf(w0.x, h4.x, ar); az = fmaf(w0.y, h4.x, az); an = fmaf(n0, h4.x, an);
      ar = fmaf(w1.x, h4.y, ar); az = fmaf(w1.y, h4.y, az); an = fmaf(n1, h4.y, an);
      ar = fmaf(w2.x, h4.z, ar); az = fmaf(w2.y, h4.z, az); an = fmaf(n2, h4.z, an);
      ar = fmaf(w3.x, h4.w, ar); az = fmaf(w3.y, h4.w, az); an = fmaf(n3, h4.w, an);
      wrz += 4 * HH; wn += 4 * HH;
    }
    if (half) {  // write partials
      red[j] = ar; red[HH + j] = az; red[2 * HH + j] = an;
    }
    __syncthreads();  // also guarantees all hs reads for this step are done
    if (!half) {
      ar += red[j]; az += red[HH + j]; an += red[2 * HH + j];
      const float* xp = xc + ((size_t)sl * BB + b) * GG;
      float r = sigmoidf_(xp[j] + bh_r + ar);
      float z = sigmoidf_(xp[HH + j] + bh_z + az);
      // NOTE: reference is n = tanh(i_n + r * (matmul_n + b_hh_n)) — bias
      // INSIDE the r-product. Round 5 dropped the r* factor; fixed here.
      float n = tanhf(xp[2 * HH + j] + r * (bh_n + an));
      float hnew = (1.f - z) * n + z * hprev;
      hprev = hnew;
      hs[j] = hnew;
      hout[(size_t)(s0 + sl) * HH + j] = hnew;
    }
    __syncthreads();  // hnew visible to all before next step's reads
  }
}

// ------- fused attention: gram -> full-row softmax -> tril mask -> PV --------
#define AR 32
__global__ __launch_bounds__(256) void attn_fused(const float* __restrict__ h_all,
                                                  float* __restrict__ out) {
  const int b = blockIdx.y;
  const int r0 = blockIdx.x * AR;
  const float* h = h_all + (size_t)b * SS * HH;  // [512][512]
  __shared__ float Ssc[AR][SS + 4];
  __shared__ float Bt[32][68];
  __shared__ float At[AR][36];
  const int tx = threadIdx.x & 15, ty = threadIdx.x >> 4;  // ty: 2 rows each

  // ---- phase 1: Ssc = h[r0:r0+32] @ h^T  (M=32, N=512, K=512) ----
  for (int nt = 0; nt < 8; ++nt) {
    const int n0 = nt * 64;
    float acc[2][4] = {};
    for (int k0 = 0; k0 < HH; k0 += 32) {
      {  // stage At 32x32
        int m = threadIdx.x >> 3, kq = (threadIdx.x & 7) << 2;
        *(float4*)&At[m][kq] =
            *(const float4*)&h[(size_t)(r0 + m) * HH + k0 + kq];
      }
#pragma unroll
      for (int i = 0; i < 2; ++i) {  // stage Bt = h[n0+n][k0+kk] transposed
        int f = threadIdx.x + 256 * i;
        int n = f >> 3, kq = (f & 7) << 2;
        float4 bv = *(const float4*)&h[(size_t)(n0 + n) * HH + k0 + kq];
        Bt[kq + 0][n] = bv.x; Bt[kq + 1][n] = bv.y;
        Bt[kq + 2][n] = bv.z; Bt[kq + 3][n] = bv.w;
      }
      __syncthreads();
#pragma unroll
      for (int kk = 0; kk < 32; ++kk) {
        float a0 = At[ty * 2 + 0][kk], a1 = At[ty * 2 + 1][kk];
        float4 b4 = *(const float4*)&Bt[kk][tx * 4];
        acc[0][0] = fmaf(a0, b4.x, acc[0][0]);
        acc[0][1] = fmaf(a0, b4.y, acc[0][1]);
        acc[0][2] = fmaf(a0, b4.z, acc[0][2]);
        acc[0][3] = fmaf(a0, b4.w, acc[0][3]);
        acc[1][0] = fmaf(a1, b4.x, acc[1][0]);
        acc[1][1] = fmaf(a1, b4.y, acc[1][1]);
        acc[1][2] = fmaf(a1, b4.z, acc[1][2]);
        acc[1][3] = fmaf(a1, b4.w, acc[1][3]);
      }
      __syncthreads();
    }
#pragma unroll
    for (int i = 0; i < 2; ++i)
#pragma unroll
      for (int j = 0; j < 4; ++j)
        Ssc[ty * 2 + i][n0 + tx * 4 + j] = acc[i][j];
  }
  __syncthreads();

  // ---- phase 2: full-row softmax, then tril mask (unrenormalized) ----
  {
    const int lane = threadIdx.x & 63, w = threadIdx.x >> 6;  // 4 waves
    for (int r = w; r < AR; r += 4) {
      const int sr = r0 + r;
      float v[8];
      float mx = -INFINITY;
#pragma unroll
      for (int i = 0; i < 8; ++i) {
        v[i] = Ssc[r][lane + i * 64];
        mx = fmaxf(mx, v[i]);
      }
#pragma unroll
      for (int off = 32; off; off >>= 1) mx = fmaxf(mx, __shfl_xor(mx, off));
      float sm = 0.f;
#pragma unroll
      for (int i = 0; i < 8; ++i) { v[i] = expf(v[i] - mx); sm += v[i]; }
#pragma unroll
      for (int off = 32; off; off >>= 1) sm += __shfl_xor(sm, off);
      const float inv = 1.f / sm;
#pragma unroll
      for (int i = 0; i < 8; ++i) {
        int c = lane + i * 64;
        Ssc[r][c] = (c <= sr) ? v[i] * inv : 0.f;
      }
    }
  }
  __syncthreads();

  // ---- phase 3: out rows = Ssc @ h  (M=32, N=512, K=512) ----
  for (int nt = 0; nt < 8; ++nt) {
    const int n0 = nt * 64;
    float acc[2][4] = {};
    for (int k0 = 0; k0 < SS; k0 += 32) {
#pragma unroll
      for (int i = 0; i < 2; ++i) {  // stage Bt = h[k0+kk][n0+n] (NN)
        int f = threadIdx.x + 256 * i;
        int n4 = (f & 15) << 2, kk = f >> 4;
        *(float4*)&Bt[kk][n4] =
            *(const float4*)&h[(size_t)(k0 + kk) * HH + n0 + n4];
      }
      __syncthreads();
#pragma unroll
      for (int kk = 0; kk < 32; ++kk) {
        float a0 = Ssc[ty * 2 + 0][k0 + kk], a1 = Ssc[ty * 2 + 1][k0 + kk];
        float4 b4 = *(const float4*)&Bt[kk][tx * 4];
        acc[0][0] = fmaf(a0, b4.x, acc[0][0]);
        acc[0][1] = fmaf(a0, b4.y, acc[0][1]);
        acc[0][2] = fmaf(a0, b4.z, acc[0][2]);
        acc[0][3] = fmaf(a0, b4.w, acc[0][3]);
        acc[1][0] = fmaf(a1, b4.x, acc[1][0]);
        acc[1][1] = fmaf(a1, b4.y, acc[1][1]);
        acc[1][2] = fmaf(a1, b4.z, acc[1][2]);
        acc[1][3] = fmaf(a1, b4.w, acc[1][3]);
      }
      __syncthreads();
    }
#pragma unroll
    for (int i = 0; i < 2; ++i) {
      float4 o = {acc[i][0], acc[i][1], acc[i][2], acc[i][3]};
      *(float4*)&out[((size_t)b * SS + r0 + ty * 2 + i) * HH + n0 + tx * 4] = o;
    }
  }
}

// ---------------------------------------------------------------------------
extern "C" void kernel_launch(void* const* d_in, const int* in_sizes, int n_in,
                              void* d_out, int out_size, void* d_ws, size_t ws_size,
                              hipStream_t stream) {
  const float* inp  = (const float*)d_in[0];
  // d_in[1] = seq_lens (all == S) — unused
  const float* W_ih = (const float*)d_in[2];
  const float* W_hh = (const float*)d_in[3];
  const float* b_ih = (const float*)d_in[4];
  const float* b_hh = (const float*)d_in[5];
  float* out = (float*)d_out;
  float* ws  = (float*)d_ws;

  // d_ws holds ONLY h_all: 64 * 512 * 512 floats = 64 MiB.
  if (ws_size < (size_t)BB * SS * HH * sizeof(float)) return;  // can't run safely
  float* h_all = ws;

  // d_out doubles as scratch until attn_fused rewrites it.
  float*  WihT = out + OUT_OFF_WIHT;
  float2* Wrz  = (float2*)(out + OUT_OFF_WRZ);
  float*  Wn   = out + OUT_OFF_WN;
  float*  xc   = out + OUT_OFF_XC;

  // 1) weight repack
  transpose_k<<<dim3(256 / 32, 1536 / 32), dim3(32, 8), 0, stream>>>(W_ih, WihT, 1536, 256);
  pack_whh<<<dim3(512 * 512 / 256), 256, 0, stream>>>(W_hh, Wrz, Wn);

  // 2) alternate x_proj chunk GEMM and GRU scan over 4 time chunks
  for (int c = 0; c < NCHUNK; ++c) {
    const int s0 = c * SC;
    xproj_gemm<<<dim3(GG / 64, SC), 256, 0, stream>>>(inp, WihT, b_ih, xc, s0);
    gru_scan_chunk<<<dim3(BB), dim3(1024), 0, stream>>>(xc, Wrz, Wn, b_hh, h_all, s0);
  }

  // 3) fused attention: gram -> softmax -> tril -> PV, writes all of d_out
  attn_fused<<<dim3(SS / AR, BB), 256, 0, stream>>>(h_all, out);
}

// Round 7
// 19164.955 us; speedup vs baseline: 1.0434x; 1.0434x over previous
//
#include <hip/hip_runtime.h>
#include <hip/hip_cooperative_groups.h>
#include <math.h>

namespace cg = cooperative_groups;

// Problem constants
#define BB 64
#define SS 512
#define DD 256
#define HH 512
#define GG 1536   // 3H
#define SC 128    // steps per x_proj chunk
#define NCHUNK 4
#define NWG 256   // cooperative WGs, each owns U hidden units
#define U 2

// d_out scratch layout (float offsets) — d_out is dead until attn_fused rewrites it
#define OUT_OFF_WIHT 0UL
#define OUT_SZ_WIHT  (256UL * 1536UL)               // 393216 floats
#define OUT_OFF_HT   (OUT_OFF_WIHT + OUT_SZ_WIHT)   // hT[2][512][64] = 65536 floats
#define OUT_SZ_HT    (2UL * 512UL * 64UL)
#define OUT_OFF_XC   (OUT_OFF_HT + OUT_SZ_HT)
#define OUT_SZ_XC    ((size_t)SC * BB * GG)         // 12582912 -> total 13041664 < 16777216

__device__ __forceinline__ float sigmoidf_(float x) {
  return 1.f / (1.f + expf(-x));
}

// ---------------- transpose: out[c][r] = in[r][c] ----------------
__global__ __launch_bounds__(256) void transpose_k(const float* __restrict__ in,
                                                   float* __restrict__ out,
                                                   int R, int C) {
  __shared__ float tile[32][33];
  int bx = blockIdx.x * 32;  // C base
  int by = blockIdx.y * 32;  // R base
  int tx = threadIdx.x, ty = threadIdx.y;  // 32 x 8
  for (int i = ty; i < 32; i += 8) {
    int r = by + i, c = bx + tx;
    if (r < R && c < C) tile[i][tx] = in[(size_t)r * C + c];
  }
  __syncthreads();
  for (int i = ty; i < 32; i += 8) {
    int c = bx + i, r = by + tx;
    if (c < C && r < R) out[(size_t)c * R + r] = tile[tx][i];
  }
}

// -------- x_proj chunk GEMM: xc[sl][b][g] = inp[b][s0+sl][:] . WihT[:][g] + b_ih[g]
__global__ __launch_bounds__(256) void xproj_gemm(const float* __restrict__ inp,
                                                  const float* __restrict__ WihT,
                                                  const float* __restrict__ b_ih,
                                                  float* __restrict__ xc, int s0) {
  const int sl = blockIdx.y;
  const int n0 = blockIdx.x * 64;
  const int srow = s0 + sl;
  const int tx = threadIdx.x & 15, ty = threadIdx.x >> 4;
  __shared__ float As[64][36];
  __shared__ float Bs[32][68];
  float acc[4][4] = {};

  for (int k0 = 0; k0 < DD; k0 += 32) {
#pragma unroll
    for (int i = 0; i < 2; ++i) {  // stage A 64x32 (rows = batches)
      int f = threadIdx.x + 256 * i;
      int m = f >> 3, kq = (f & 7) << 2;
      *(float4*)&As[m][kq] =
          *(const float4*)&inp[((size_t)m * SS + srow) * DD + k0 + kq];
    }
#pragma unroll
    for (int i = 0; i < 2; ++i) {  // stage B 32x64
      int f = threadIdx.x + 256 * i;
      int n4 = (f & 15) << 2, kk = f >> 4;
      *(float4*)&Bs[kk][n4] =
          *(const float4*)&WihT[(size_t)(k0 + kk) * GG + n0 + n4];
    }
    __syncthreads();
#pragma unroll
    for (int kk = 0; kk < 32; ++kk) {
      float a[4];
#pragma unroll
      for (int i = 0; i < 4; ++i) a[i] = As[ty * 4 + i][kk];
      float4 b4 = *(const float4*)&Bs[kk][tx * 4];
      float bb[4] = {b4.x, b4.y, b4.z, b4.w};
#pragma unroll
      for (int i = 0; i < 4; ++i)
#pragma unroll
        for (int j = 0; j < 4; ++j) acc[i][j] = fmaf(a[i], bb[j], acc[i][j]);
    }
    __syncthreads();
  }
  const float g0 = b_ih[n0 + tx * 4 + 0], g1 = b_ih[n0 + tx * 4 + 1];
  const float g2 = b_ih[n0 + tx * 4 + 2], g3 = b_ih[n0 + tx * 4 + 3];
#pragma unroll
  for (int i = 0; i < 4; ++i) {
    int m = ty * 4 + i;  // batch
    float4 o = {acc[i][0] + g0, acc[i][1] + g1, acc[i][2] + g2, acc[i][3] + g3};
    *(float4*)&xc[((size_t)sl * BB + m) * GG + n0 + tx * 4] = o;
  }
}

// ---------------- cooperative persistent GRU scan -----------------
// 256 WGs x 512 threads; WG w owns hidden units j0=2w, j0+1 and keeps their
// 6 weight rows (3 gates x 2 units x 512) in LDS for the whole chunk.
// h state lives in hT[2][512][64] (k-major, batch-minor) double-buffered.
// Thread t: b = t&63, q = t>>6 (k-range 64q..64q+63).
__global__ __launch_bounds__(512) void gru_coop(const float* __restrict__ xc,
                                                const float* __restrict__ W_hh,
                                                const float* __restrict__ b_hh,
                                                float* __restrict__ hT,
                                                float* __restrict__ h_all,
                                                int s0) {
  const int w = blockIdx.x;
  const int j0 = w * U;
  const int t = threadIdx.x;
  const int b = t & 63;
  const int q = t >> 6;
  __shared__ float Wlds[6][512];      // [u*3+g][k]
  __shared__ float red[6][64][9];     // [gu][b][q], pad 9 (conflict-free writes)

  // load this WG's weight rows once (coalesced: row g*512+j of W_hh is contiguous)
  for (int idx = t; idx < 6 * 512; idx += 512) {
    int gu = idx >> 9, k = idx & 511;
    int u = gu / 3, g = gu % 3;
    Wlds[gu][k] = W_hh[(size_t)(g * HH + j0 + u) * HH + k];
  }
  // reducer-thread state
  float hprev = 0.f, bh_r = 0.f, bh_z = 0.f, bh_n = 0.f;
  if (t < 64 * U) {
    const int u = t >> 6;
    if (s0 == 0) {
      hT[(size_t)(j0 + u) * 64 + b] = 0.f;       // init read-buffer 0
    } else {
      hprev = hT[(size_t)(j0 + u) * 64 + b];     // carried from prev chunk
    }
    bh_r = b_hh[j0 + u]; bh_z = b_hh[HH + j0 + u]; bh_n = b_hh[2 * HH + j0 + u];
  }
  __syncthreads();
  cg::this_grid().sync();  // hT[0] globally visible

  for (int sl = 0; sl < SC; ++sl) {
    const int rb = sl & 1, wb = rb ^ 1;
    // prefetch x_proj gate inputs (independent of h)
    float xr = 0.f, xz = 0.f, xn = 0.f;
    if (t < 64 * U) {
      const int u = t >> 6;
      const float* xp = xc + ((size_t)sl * BB + b) * GG;
      xr = xp[j0 + u]; xz = xp[HH + j0 + u]; xn = xp[2 * HH + j0 + u];
    }
    // dot phase: 6 partial dots over this thread's k-range
    float a0 = 0.f, a1 = 0.f, a2 = 0.f, a3 = 0.f, a4 = 0.f, a5 = 0.f;
    const float* hp = hT + (size_t)rb * (HH * 64) + (size_t)q * 64 * 64 + b;
    const int kq = q * 64;
    float h0 = hp[0 * 64], h1 = hp[1 * 64], h2 = hp[2 * 64], h3 = hp[3 * 64];
#pragma unroll
    for (int kk = 0; kk < 64; kk += 4) {
      float p0 = 0.f, p1 = 0.f, p2 = 0.f, p3 = 0.f;
      if (kk < 60) {  // compile-time after unroll
        p0 = hp[(kk + 4) * 64]; p1 = hp[(kk + 5) * 64];
        p2 = hp[(kk + 6) * 64]; p3 = hp[(kk + 7) * 64];
      }
      const float4 w0 = *(const float4*)&Wlds[0][kq + kk];
      const float4 w1 = *(const float4*)&Wlds[1][kq + kk];
      const float4 w2 = *(const float4*)&Wlds[2][kq + kk];
      const float4 w3 = *(const float4*)&Wlds[3][kq + kk];
      const float4 w4 = *(const float4*)&Wlds[4][kq + kk];
      const float4 w5 = *(const float4*)&Wlds[5][kq + kk];
      a0 = fmaf(w0.x, h0, a0); a1 = fmaf(w1.x, h0, a1); a2 = fmaf(w2.x, h0, a2);
      a3 = fmaf(w3.x, h0, a3); a4 = fmaf(w4.x, h0, a4); a5 = fmaf(w5.x, h0, a5);
      a0 = fmaf(w0.y, h1, a0); a1 = fmaf(w1.y, h1, a1); a2 = fmaf(w2.y, h1, a2);
      a3 = fmaf(w3.y, h1, a3); a4 = fmaf(w4.y, h1, a4); a5 = fmaf(w5.y, h1, a5);
      a0 = fmaf(w0.z, h2, a0); a1 = fmaf(w1.z, h2, a1); a2 = fmaf(w2.z, h2, a2);
      a3 = fmaf(w3.z, h2, a3); a4 = fmaf(w4.z, h2, a4); a5 = fmaf(w5.z, h2, a5);
      a0 = fmaf(w0.w, h3, a0); a1 = fmaf(w1.w, h3, a1); a2 = fmaf(w2.w, h3, a2);
      a3 = fmaf(w3.w, h3, a3); a4 = fmaf(w4.w, h3, a4); a5 = fmaf(w5.w, h3, a5);
      h0 = p0; h1 = p1; h2 = p2; h3 = p3;
    }
    red[0][b][q] = a0; red[1][b][q] = a1; red[2][b][q] = a2;
    red[3][b][q] = a3; red[4][b][q] = a4; red[5][b][q] = a5;
    __syncthreads();
    if (t < 64 * U) {
      const int u = t >> 6;
      float sr = 0.f, sz = 0.f, sn = 0.f;
#pragma unroll
      for (int qq = 0; qq < 8; ++qq) {
        sr += red[u * 3 + 0][b][qq];
        sz += red[u * 3 + 1][b][qq];
        sn += red[u * 3 + 2][b][qq];
      }
      float r = sigmoidf_(xr + bh_r + sr);
      float z = sigmoidf_(xz + bh_z + sz);
      float n = tanhf(xn + r * (bh_n + sn));   // bias inside r-product (ref math)
      float hnew = (1.f - z) * n + z * hprev;
      hprev = hnew;
      hT[(size_t)wb * (HH * 64) + (size_t)(j0 + u) * 64 + b] = hnew;
      h_all[((size_t)b * SS + (s0 + sl)) * HH + (j0 + u)] = hnew;
    }
    __syncthreads();
    cg::this_grid().sync();  // hT[wb] visible to all WGs for next step
  }
}

// ------- fused attention: gram -> full-row softmax -> tril mask -> PV --------
#define AR 32
__global__ __launch_bounds__(256) void attn_fused(const float* __restrict__ h_all,
                                                  float* __restrict__ out) {
  const int b = blockIdx.y;
  const int r0 = blockIdx.x * AR;
  const float* h = h_all + (size_t)b * SS * HH;  // [512][512]
  __shared__ float Ssc[AR][SS + 4];
  __shared__ float Bt[32][68];
  __shared__ float At[AR][36];
  const int tx = threadIdx.x & 15, ty = threadIdx.x >> 4;  // ty: 2 rows each

  // ---- phase 1: Ssc = h[r0:r0+32] @ h^T  (M=32, N=512, K=512) ----
  for (int nt = 0; nt < 8; ++nt) {
    const int n0 = nt * 64;
    float acc[2][4] = {};
    for (int k0 = 0; k0 < HH; k0 += 32) {
      {  // stage At 32x32
        int m = threadIdx.x >> 3, kq = (threadIdx.x & 7) << 2;
        *(float4*)&At[m][kq] =
            *(const float4*)&h[(size_t)(r0 + m) * HH + k0 + kq];
      }
#pragma unroll
      for (int i = 0; i < 2; ++i) {  // stage Bt = h[n0+n][k0+kk] transposed
        int f = threadIdx.x + 256 * i;
        int n = f >> 3, kq = (f & 7) << 2;
        float4 bv = *(const float4*)&h[(size_t)(n0 + n) * HH + k0 + kq];
        Bt[kq + 0][n] = bv.x; Bt[kq + 1][n] = bv.y;
        Bt[kq + 2][n] = bv.z; Bt[kq + 3][n] = bv.w;
      }
      __syncthreads();
#pragma unroll
      for (int kk = 0; kk < 32; ++kk) {
        float a0 = At[ty * 2 + 0][kk], a1 = At[ty * 2 + 1][kk];
        float4 b4 = *(const float4*)&Bt[kk][tx * 4];
        acc[0][0] = fmaf(a0, b4.x, acc[0][0]);
        acc[0][1] = fmaf(a0, b4.y, acc[0][1]);
        acc[0][2] = fmaf(a0, b4.z, acc[0][2]);
        acc[0][3] = fmaf(a0, b4.w, acc[0][3]);
        acc[1][0] = fmaf(a1, b4.x, acc[1][0]);
        acc[1][1] = fmaf(a1, b4.y, acc[1][1]);
        acc[1][2] = fmaf(a1, b4.z, acc[1][2]);
        acc[1][3] = fmaf(a1, b4.w, acc[1][3]);
      }
      __syncthreads();
    }
#pragma unroll
    for (int i = 0; i < 2; ++i)
#pragma unroll
      for (int j = 0; j < 4; ++j)
        Ssc[ty * 2 + i][n0 + tx * 4 + j] = acc[i][j];
  }
  __syncthreads();

  // ---- phase 2: full-row softmax, then tril mask (unrenormalized) ----
  {
    const int lane = threadIdx.x & 63, w = threadIdx.x >> 6;  // 4 waves
    for (int r = w; r < AR; r += 4) {
      const int sr = r0 + r;
      float v[8];
      float mx = -INFINITY;
#pragma unroll
      for (int i = 0; i < 8; ++i) {
        v[i] = Ssc[r][lane + i * 64];
        mx = fmaxf(mx, v[i]);
      }
#pragma unroll
      for (int off = 32; off; off >>= 1) mx = fmaxf(mx, __shfl_xor(mx, off));
      float sm = 0.f;
#pragma unroll
      for (int i = 0; i < 8; ++i) { v[i] = expf(v[i] - mx); sm += v[i]; }
#pragma unroll
      for (int off = 32; off; off >>= 1) sm += __shfl_xor(sm, off);
      const float inv = 1.f / sm;
#pragma unroll
      for (int i = 0; i < 8; ++i) {
        int c = lane + i * 64;
        Ssc[r][c] = (c <= sr) ? v[i] * inv : 0.f;
      }
    }
  }
  __syncthreads();

  // ---- phase 3: out rows = Ssc @ h  (M=32, N=512, K=512) ----
  for (int nt = 0; nt < 8; ++nt) {
    const int n0 = nt * 64;
    float acc[2][4] = {};
    for (int k0 = 0; k0 < SS; k0 += 32) {
#pragma unroll
      for (int i = 0; i < 2; ++i) {  // stage Bt = h[k0+kk][n0+n] (NN)
        int f = threadIdx.x + 256 * i;
        int n4 = (f & 15) << 2, kk = f >> 4;
        *(float4*)&Bt[kk][n4] =
            *(const float4*)&h[(size_t)(k0 + kk) * HH + n0 + n4];
      }
      __syncthreads();
#pragma unroll
      for (int kk = 0; kk < 32; ++kk) {
        float a0 = Ssc[ty * 2 + 0][k0 + kk], a1 = Ssc[ty * 2 + 1][k0 + kk];
        float4 b4 = *(const float4*)&Bt[kk][tx * 4];
        acc[0][0] = fmaf(a0, b4.x, acc[0][0]);
        acc[0][1] = fmaf(a0, b4.y, acc[0][1]);
        acc[0][2] = fmaf(a0, b4.z, acc[0][2]);
        acc[0][3] = fmaf(a0, b4.w, acc[0][3]);
        acc[1][0] = fmaf(a1, b4.x, acc[1][0]);
        acc[1][1] = fmaf(a1, b4.y, acc[1][1]);
        acc[1][2] = fmaf(a1, b4.z, acc[1][2]);
        acc[1][3] = fmaf(a1, b4.w, acc[1][3]);
      }
      __syncthreads();
    }
#pragma unroll
    for (int i = 0; i < 2; ++i) {
      float4 o = {acc[i][0], acc[i][1], acc[i][2], acc[i][3]};
      *(float4*)&out[((size_t)b * SS + r0 + ty * 2 + i) * HH + n0 + tx * 4] = o;
    }
  }
}

// ---------------------------------------------------------------------------
extern "C" void kernel_launch(void* const* d_in, const int* in_sizes, int n_in,
                              void* d_out, int out_size, void* d_ws, size_t ws_size,
                              hipStream_t stream) {
  const float* inp  = (const float*)d_in[0];
  // d_in[1] = seq_lens (all == S) — unused
  const float* W_ih = (const float*)d_in[2];
  const float* W_hh = (const float*)d_in[3];
  const float* b_ih = (const float*)d_in[4];
  const float* b_hh = (const float*)d_in[5];
  float* out = (float*)d_out;
  float* ws  = (float*)d_ws;

  // d_ws holds ONLY h_all: 64 * 512 * 512 floats = 64 MiB.
  if (ws_size < (size_t)BB * SS * HH * sizeof(float)) return;
  float* h_all = ws;

  // d_out doubles as scratch until attn_fused rewrites it.
  float* WihT = out + OUT_OFF_WIHT;
  float* hT   = out + OUT_OFF_HT;
  float* xc   = out + OUT_OFF_XC;

  // 1) transpose W_ih for the x_proj GEMM
  transpose_k<<<dim3(256 / 32, 1536 / 32), dim3(32, 8), 0, stream>>>(W_ih, WihT, 1536, 256);

  // 2) alternate x_proj chunk GEMM and cooperative GRU scan over 4 time chunks
  int s0s[NCHUNK];
  for (int c = 0; c < NCHUNK; ++c) {
    s0s[c] = c * SC;
    xproj_gemm<<<dim3(GG / 64, SC), 256, 0, stream>>>(inp, WihT, b_ih, xc, s0s[c]);
    void* args[] = {(void*)&xc, (void*)&W_hh, (void*)&b_hh,
                    (void*)&hT, (void*)&h_all, (void*)&s0s[c]};
    hipLaunchCooperativeKernel((void*)gru_coop, dim3(NWG), dim3(512), args, 0, stream);
  }

  // 3) fused attention: gram -> softmax -> tril -> PV, writes all of d_out
  attn_fused<<<dim3(SS / AR, BB), 256, 0, stream>>>(h_all, out);
}

// Round 9
// 9515.235 us; speedup vs baseline: 2.1016x; 2.0141x over previous
//
#include <hip/hip_runtime.h>
#include <math.h>

// Problem constants
#define BB 64
#define SS 512
#define DD 256
#define HH 512
#define GG 1536   // 3H
#define SC 128    // steps per x_proj chunk
#define NCHUNK 4
#define NWG2 128  // persistent WGs, each owns U2 hidden units
#define U2 4

// d_out scratch layout (float offsets) — d_out is dead until attn_fused rewrites it
#define OUT_OFF_WIHT 0UL
#define OUT_SZ_WIHT  (256UL * 1536UL)               // 393216 floats
#define OUT_OFF_HT   (OUT_OFF_WIHT + OUT_SZ_WIHT)   // hT[2][512][64] = 65536 floats
#define OUT_SZ_HT    (2UL * 512UL * 64UL)
#define OUT_OFF_XC   (OUT_OFF_HT + OUT_SZ_HT)
#define OUT_SZ_XC    ((size_t)SC * BB * GG)         // 12582912
#define OUT_OFF_BAR  (OUT_OFF_XC + OUT_SZ_XC)       // 13041664; +64 floats for barrier
// total 13041728 < 16777216 ✓

__device__ __forceinline__ float sigmoidf_(float x) {
  return 1.f / (1.f + expf(-x));
}

// ---------------- transpose: out[c][r] = in[r][c] ----------------
__global__ __launch_bounds__(256) void transpose_k(const float* __restrict__ in,
                                                   float* __restrict__ out,
                                                   int R, int C) {
  __shared__ float tile[32][33];
  int bx = blockIdx.x * 32;  // C base
  int by = blockIdx.y * 32;  // R base
  int tx = threadIdx.x, ty = threadIdx.y;  // 32 x 8
  for (int i = ty; i < 32; i += 8) {
    int r = by + i, c = bx + tx;
    if (r < R && c < C) tile[i][tx] = in[(size_t)r * C + c];
  }
  __syncthreads();
  for (int i = ty; i < 32; i += 8) {
    int c = bx + i, r = by + tx;
    if (c < C && r < R) out[(size_t)c * R + r] = tile[tx][i];
  }
}

// -------- barrier state init (re-run every kernel_launch; ws/out are poisoned)
__global__ void init_bar(int* bar) {
  bar[0] = 0;   // arrival counter
  bar[32] = 0;  // generation (separate cacheline)
}

// -------- x_proj chunk GEMM: xc[sl][b][g] = inp[b][s0+sl][:] . WihT[:][g] + b_ih[g]
__global__ __launch_bounds__(256) void xproj_gemm(const float* __restrict__ inp,
                                                  const float* __restrict__ WihT,
                                                  const float* __restrict__ b_ih,
                                                  float* __restrict__ xc, int s0) {
  const int sl = blockIdx.y;
  const int n0 = blockIdx.x * 64;
  const int srow = s0 + sl;
  const int tx = threadIdx.x & 15, ty = threadIdx.x >> 4;
  __shared__ float As[64][36];
  __shared__ float Bs[32][68];
  float acc[4][4] = {};

  for (int k0 = 0; k0 < DD; k0 += 32) {
#pragma unroll
    for (int i = 0; i < 2; ++i) {  // stage A 64x32 (rows = batches)
      int f = threadIdx.x + 256 * i;
      int m = f >> 3, kq = (f & 7) << 2;
      *(float4*)&As[m][kq] =
          *(const float4*)&inp[((size_t)m * SS + srow) * DD + k0 + kq];
    }
#pragma unroll
    for (int i = 0; i < 2; ++i) {  // stage B 32x64
      int f = threadIdx.x + 256 * i;
      int n4 = (f & 15) << 2, kk = f >> 4;
      *(float4*)&Bs[kk][n4] =
          *(const float4*)&WihT[(size_t)(k0 + kk) * GG + n0 + n4];
    }
    __syncthreads();
#pragma unroll
    for (int kk = 0; kk < 32; ++kk) {
      float a[4];
#pragma unroll
      for (int i = 0; i < 4; ++i) a[i] = As[ty * 4 + i][kk];
      float4 b4 = *(const float4*)&Bs[kk][tx * 4];
      float bb[4] = {b4.x, b4.y, b4.z, b4.w};
#pragma unroll
      for (int i = 0; i < 4; ++i)
#pragma unroll
        for (int j = 0; j < 4; ++j) acc[i][j] = fmaf(a[i], bb[j], acc[i][j]);
    }
    __syncthreads();
  }
  const float g0 = b_ih[n0 + tx * 4 + 0], g1 = b_ih[n0 + tx * 4 + 1];
  const float g2 = b_ih[n0 + tx * 4 + 2], g3 = b_ih[n0 + tx * 4 + 3];
#pragma unroll
  for (int i = 0; i < 4; ++i) {
    int m = ty * 4 + i;  // batch
    float4 o = {acc[i][0] + g0, acc[i][1] + g1, acc[i][2] + g2, acc[i][3] + g3};
    *(float4*)&xc[((size_t)sl * BB + m) * GG + n0 + tx * 4] = o;
  }
}

// -------- lightweight grid barrier: thread-0 arrival + generation spin --------
// Bounded spin: on pathological failure we break out (test then fails absmax)
// instead of hanging the GPU/container.
__device__ __forceinline__ void grid_bar(int* cnt, int* gen, int target) {
  __syncthreads();
  if (threadIdx.x == 0) {
    __threadfence();  // device-scope: publish this WG's global writes
    int prev = __hip_atomic_fetch_add(cnt, 1, __ATOMIC_ACQ_REL,
                                      __HIP_MEMORY_SCOPE_AGENT);
    if (prev == NWG2 - 1) {
      __hip_atomic_store(cnt, 0, __ATOMIC_RELAXED, __HIP_MEMORY_SCOPE_AGENT);
      __hip_atomic_store(gen, target, __ATOMIC_RELEASE, __HIP_MEMORY_SCOPE_AGENT);
    } else {
      int tries = 0;
      while (__hip_atomic_load(gen, __ATOMIC_ACQUIRE,
                               __HIP_MEMORY_SCOPE_AGENT) < target) {
        __builtin_amdgcn_s_sleep(1);
        if (++tries > 200000) break;  // safety valve: never hang the device
      }
    }
  }
  __syncthreads();
}

// ---------------- persistent GRU scan (all WGs co-resident by capacity) ------
// 128 WGs x 512 threads; WG w owns units j0=4w..j0+3; 12 weight rows (24 KB)
// live in LDS for the whole chunk. h state: hT[2][512][64], double-buffered.
// Thread t: b = t&63, q = t>>6 (k-range 64q..64q+63). q is wave-uniform ->
// Wlds reads are LDS broadcasts; hT reads are lane-coalesced on b.
__global__ __launch_bounds__(512) void gru_coop(const float* __restrict__ xc,
                                                const float* __restrict__ W_hh,
                                                const float* __restrict__ b_hh,
                                                float* __restrict__ hT,
                                                float* __restrict__ h_all,
                                                int* __restrict__ bar,
                                                int s0, int barbase) {
  const int w = blockIdx.x;
  const int j0 = w * U2;
  const int t = threadIdx.x;
  const int b = t & 63;
  const int q = t >> 6;
  __shared__ float Wlds[12][512];   // [u*3+g][k]  24 KB
  __shared__ float red[12][64][9];  // [gu][b][q]  27.6 KB (stride 9: 2-way banks)

  int* cnt = bar;
  int* gen = bar + 32;

  // load this WG's 12 weight rows once (coalesced)
  for (int idx = t; idx < 12 * 512; idx += 512) {
    int gu = idx >> 9, k = idx & 511;
    int u = gu / 3, g = gu % 3;   // gu = u*3 + g
    Wlds[gu][k] = W_hh[(size_t)(g * HH + j0 + u) * HH + k];
  }
  // reducer-thread state (t < 256: u = t>>6, batch b)
  float hprev = 0.f, bh_r = 0.f, bh_z = 0.f, bh_n = 0.f;
  if (t < 64 * U2) {
    const int u = t >> 6;
    if (s0 == 0) {
      hT[(size_t)(j0 + u) * 64 + b] = 0.f;     // init read-buffer 0
    } else {
      hprev = hT[(size_t)(j0 + u) * 64 + b];   // carried from prev chunk
    }
    bh_r = b_hh[j0 + u]; bh_z = b_hh[HH + j0 + u]; bh_n = b_hh[2 * HH + j0 + u];
  }
  grid_bar(cnt, gen, barbase + 1);  // hT[0] globally visible

  for (int sl = 0; sl < SC; ++sl) {
    const int rb = sl & 1, wb = rb ^ 1;
    // x_proj gate inputs (independent of h)
    float xr = 0.f, xz = 0.f, xn = 0.f;
    if (t < 64 * U2) {
      const int u = t >> 6;
      const float* xp = xc + ((size_t)sl * BB + b) * GG;
      xr = xp[j0 + u]; xz = xp[HH + j0 + u]; xn = xp[2 * HH + j0 + u];
    }
    // dot phase: 12 partial dots over this thread's 64-k range
    float a[12] = {};
    const float* hp = hT + (size_t)rb * (HH * 64) + (size_t)q * 64 * 64 + b;
    const int kq = q * 64;
#pragma unroll
    for (int kk = 0; kk < 64; kk += 4) {
      float h0 = hp[(kk + 0) * 64];
      float h1 = hp[(kk + 1) * 64];
      float h2 = hp[(kk + 2) * 64];
      float h3 = hp[(kk + 3) * 64];
#pragma unroll
      for (int gu = 0; gu < 12; ++gu) {
        const float4 wv = *(const float4*)&Wlds[gu][kq + kk];
        a[gu] = fmaf(wv.x, h0, a[gu]);
        a[gu] = fmaf(wv.y, h1, a[gu]);
        a[gu] = fmaf(wv.z, h2, a[gu]);
        a[gu] = fmaf(wv.w, h3, a[gu]);
      }
    }
#pragma unroll
    for (int gu = 0; gu < 12; ++gu) red[gu][b][q] = a[gu];
    __syncthreads();
    if (t < 64 * U2) {
      const int u = t >> 6;
      float sr = 0.f, sz = 0.f, sn = 0.f;
#pragma unroll
      for (int qq = 0; qq < 8; ++qq) {
        sr += red[u * 3 + 0][b][qq];
        sz += red[u * 3 + 1][b][qq];
        sn += red[u * 3 + 2][b][qq];
      }
      float r = sigmoidf_(xr + bh_r + sr);
      float z = sigmoidf_(xz + bh_z + sz);
      float n = tanhf(xn + r * (bh_n + sn));   // bias inside r-product (ref math)
      float hnew = (1.f - z) * n + z * hprev;
      hprev = hnew;
      hT[(size_t)wb * (HH * 64) + (size_t)(j0 + u) * 64 + b] = hnew;
      h_all[((size_t)b * SS + (s0 + sl)) * HH + (j0 + u)] = hnew;
    }
    grid_bar(cnt, gen, barbase + sl + 2);  // hT[wb] visible to all WGs
  }
}

// ------- fused attention: gram -> full-row softmax -> tril mask -> PV --------
#define AR 32
__global__ __launch_bounds__(256) void attn_fused(const float* __restrict__ h_all,
                                                  float* __restrict__ out) {
  const int b = blockIdx.y;
  const int r0 = blockIdx.x * AR;
  const float* h = h_all + (size_t)b * SS * HH;  // [512][512]
  __shared__ float Ssc[AR][SS + 4];
  __shared__ float Bt[32][68];
  __shared__ float At[AR][36];
  const int tx = threadIdx.x & 15, ty = threadIdx.x >> 4;  // ty: 2 rows each

  // ---- phase 1: Ssc = h[r0:r0+32] @ h^T  (M=32, N=512, K=512) ----
  for (int nt = 0; nt < 8; ++nt) {
    const int n0 = nt * 64;
    float acc[2][4] = {};
    for (int k0 = 0; k0 < HH; k0 += 32) {
      {  // stage At 32x32
        int m = threadIdx.x >> 3, kq = (threadIdx.x & 7) << 2;
        *(float4*)&At[m][kq] =
            *(const float4*)&h[(size_t)(r0 + m) * HH + k0 + kq];
      }
#pragma unroll
      for (int i = 0; i < 2; ++i) {  // stage Bt = h[n0+n][k0+kk] transposed
        int f = threadIdx.x + 256 * i;
        int n = f >> 3, kq = (f & 7) << 2;
        float4 bv = *(const float4*)&h[(size_t)(n0 + n) * HH + k0 + kq];
        Bt[kq + 0][n] = bv.x; Bt[kq + 1][n] = bv.y;
        Bt[kq + 2][n] = bv.z; Bt[kq + 3][n] = bv.w;
      }
      __syncthreads();
#pragma unroll
      for (int kk = 0; kk < 32; ++kk) {
        float a0 = At[ty * 2 + 0][kk], a1 = At[ty * 2 + 1][kk];
        float4 b4 = *(const float4*)&Bt[kk][tx * 4];
        acc[0][0] = fmaf(a0, b4.x, acc[0][0]);
        acc[0][1] = fmaf(a0, b4.y, acc[0][1]);
        acc[0][2] = fmaf(a0, b4.z, acc[0][2]);
        acc[0][3] = fmaf(a0, b4.w, acc[0][3]);
        acc[1][0] = fmaf(a1, b4.x, acc[1][0]);
        acc[1][1] = fmaf(a1, b4.y, acc[1][1]);
        acc[1][2] = fmaf(a1, b4.z, acc[1][2]);
        acc[1][3] = fmaf(a1, b4.w, acc[1][3]);
      }
      __syncthreads();
    }
#pragma unroll
    for (int i = 0; i < 2; ++i)
#pragma unroll
      for (int j = 0; j < 4; ++j)
        Ssc[ty * 2 + i][n0 + tx * 4 + j] = acc[i][j];
  }
  __syncthreads();

  // ---- phase 2: full-row softmax, then tril mask (unrenormalized) ----
  {
    const int lane = threadIdx.x & 63, w = threadIdx.x >> 6;  // 4 waves
    for (int r = w; r < AR; r += 4) {
      const int sr = r0 + r;
      float v[8];
      float mx = -INFINITY;
#pragma unroll
      for (int i = 0; i < 8; ++i) {
        v[i] = Ssc[r][lane + i * 64];
        mx = fmaxf(mx, v[i]);
      }
#pragma unroll
      for (int off = 32; off; off >>= 1) mx = fmaxf(mx, __shfl_xor(mx, off));
      float sm = 0.f;
#pragma unroll
      for (int i = 0; i < 8; ++i) { v[i] = expf(v[i] - mx); sm += v[i]; }
#pragma unroll
      for (int off = 32; off; off >>= 1) sm += __shfl_xor(sm, off);
      const float inv = 1.f / sm;
#pragma unroll
      for (int i = 0; i < 8; ++i) {
        int c = lane + i * 64;
        Ssc[r][c] = (c <= sr) ? v[i] * inv : 0.f;
      }
    }
  }
  __syncthreads();

  // ---- phase 3: out rows = Ssc @ h  (M=32, N=512, K=512) ----
  for (int nt = 0; nt < 8; ++nt) {
    const int n0 = nt * 64;
    float acc[2][4] = {};
    for (int k0 = 0; k0 < SS; k0 += 32) {
#pragma unroll
      for (int i = 0; i < 2; ++i) {  // stage Bt = h[k0+kk][n0+n] (NN)
        int f = threadIdx.x + 256 * i;
        int n4 = (f & 15) << 2, kk = f >> 4;
        *(float4*)&Bt[kk][n4] =
            *(const float4*)&h[(size_t)(k0 + kk) * HH + n0 + n4];
      }
      __syncthreads();
#pragma unroll
      for (int kk = 0; kk < 32; ++kk) {
        float a0 = Ssc[ty * 2 + 0][k0 + kk], a1 = Ssc[ty * 2 + 1][k0 + kk];
        float4 b4 = *(const float4*)&Bt[kk][tx * 4];
        acc[0][0] = fmaf(a0, b4.x, acc[0][0]);
        acc[0][1] = fmaf(a0, b4.y, acc[0][1]);
        acc[0][2] = fmaf(a0, b4.z, acc[0][2]);
        acc[0][3] = fmaf(a0, b4.w, acc[0][3]);
        acc[1][0] = fmaf(a1, b4.x, acc[1][0]);
        acc[1][1] = fmaf(a1, b4.y, acc[1][1]);
        acc[1][2] = fmaf(a1, b4.z, acc[1][2]);
        acc[1][3] = fmaf(a1, b4.w, acc[1][3]);
      }
      __syncthreads();
    }
#pragma unroll
    for (int i = 0; i < 2; ++i) {
      float4 o = {acc[i][0], acc[i][1], acc[i][2], acc[i][3]};
      *(float4*)&out[((size_t)b * SS + r0 + ty * 2 + i) * HH + n0 + tx * 4] = o;
    }
  }
}

// ---------------------------------------------------------------------------
extern "C" void kernel_launch(void* const* d_in, const int* in_sizes, int n_in,
                              void* d_out, int out_size, void* d_ws, size_t ws_size,
                              hipStream_t stream) {
  const float* inp  = (const float*)d_in[0];
  // d_in[1] = seq_lens (all == S) — unused
  const float* W_ih = (const float*)d_in[2];
  const float* W_hh = (const float*)d_in[3];
  const float* b_ih = (const float*)d_in[4];
  const float* b_hh = (const float*)d_in[5];
  float* out = (float*)d_out;
  float* ws  = (float*)d_ws;

  // d_ws holds ONLY h_all: 64 * 512 * 512 floats = 64 MiB.
  if (ws_size < (size_t)BB * SS * HH * sizeof(float)) return;
  float* h_all = ws;

  // d_out doubles as scratch until attn_fused rewrites it.
  float* WihT = out + OUT_OFF_WIHT;
  float* hT   = out + OUT_OFF_HT;
  float* xc   = out + OUT_OFF_XC;
  int*   bar  = (int*)(out + OUT_OFF_BAR);

  // 1) transpose W_ih; zero barrier state (out is poisoned each launch)
  transpose_k<<<dim3(256 / 32, 1536 / 32), dim3(32, 8), 0, stream>>>(W_ih, WihT, 1536, 256);
  init_bar<<<1, 1, 0, stream>>>(bar);

  // 2) alternate x_proj chunk GEMM and persistent GRU scan over 4 time chunks.
  //    Normal launch: 128 WGs x 512 thr (1024 waves, 52 KB LDS) is trivially
  //    all-co-resident on 256 CUs, which is all grid_bar needs.
  for (int c = 0; c < NCHUNK; ++c) {
    const int s0 = c * SC;
    const int base = c * (SC + 1);
    xproj_gemm<<<dim3(GG / 64, SC), 256, 0, stream>>>(inp, WihT, b_ih, xc, s0);
    gru_coop<<<dim3(NWG2), dim3(512), 0, stream>>>(xc, W_hh, b_hh, hT, h_all,
                                                   bar, s0, base);
  }

  // 3) fused attention: gram -> softmax -> tril -> PV, writes all of d_out
  attn_fused<<<dim3(SS / AR, BB), 256, 0, stream>>>(h_all, out);
}